// Round 6
// baseline (154.084 us; speedup 1.0000x reference)
//
#include <hip/hip_runtime.h>
#include <hip/hip_bf16.h>
#include <hip/hip_fp16.h>
#include <cstdint>

typedef __attribute__((ext_vector_type(8))) short s16x8;
typedef __attribute__((ext_vector_type(4))) short s16x4;
typedef __attribute__((ext_vector_type(8))) _Float16 f16x8;
typedef __attribute__((ext_vector_type(4))) _Float16 f16x4;
typedef __attribute__((ext_vector_type(4))) float f32x4;

__device__ __forceinline__ void gload16(const void* g, void* l){
  __builtin_amdgcn_global_load_lds((const __attribute__((address_space(1))) void*)g,
                                   (__attribute__((address_space(3))) void*)l, 16, 0, 0);
}

// ---------------- pre-pass: fp32 -> fp16 ----------------
__global__ void convert_f16(const float* __restrict__ in, ushort* __restrict__ out, int n4){
  int i = blockIdx.x * blockDim.x + threadIdx.x;
  if (i >= n4) return;
  const f32x4 v = ((const f32x4*)in)[i];
  f16x4 o;
#pragma unroll
  for (int j = 0; j < 4; ++j) o[j] = (_Float16)v[j];
  ((f16x4*)out)[i] = o;
}

// transpose + convert: in[K][N] f32 -> outT[N][K] fp16
__global__ void transpose_f16(const float* __restrict__ in, ushort* __restrict__ outT,
                              int K, int N){
  __shared__ float tile[32][33];
  const int kb = blockIdx.y * 32, nb = blockIdx.x * 32;
  const int tx = threadIdx.x & 31, ty = threadIdx.x >> 5;  // ty: 0..7
#pragma unroll
  for (int r = 0; r < 32; r += 8)
    tile[ty + r][tx] = in[(size_t)(kb + ty + r) * N + nb + tx];
  __syncthreads();
#pragma unroll
  for (int r = 0; r < 32; r += 8){
    const float v = tile[tx][ty + r];
    const _Float16 h = (_Float16)v;
    outT[(size_t)(nb + ty + r) * K + kb + tx] = __builtin_bit_cast(ushort, h);
  }
}

// W3 (512x10 f32) -> W3T (10x512 f32)
__global__ void transpose_w3(const float* __restrict__ W3, float* __restrict__ W3T){
  const int k = threadIdx.x;  // 512 threads
#pragma unroll
  for (int c = 0; c < 10; ++c) W3T[c * 512 + k] = W3[k * 10 + c];
}

// ---- 256x256-tile fp16 GEMM, phase-staggered half-tiles + counted vmcnt --------
// A: M x K fp16 row-major.  B: N x K fp16 row-major (pre-transposed weights).
// 8 waves (2M x 4N), per-wave 128x64 output; phase = one C-quadrant (mh,nh) x K=64.
// LDS (halfwords): A plane par at par*16384, half mh at +mh*8192
//                    (A-half mh = [wm][64 rows][64 k], row r of half: wm*64+r)
//                  B plane par at 32768+par*16384, half nh at +nh*8192
//                    (B-half nh = [wn][32 rows][64 k], row of half: wn*32+r)
// Stage order per tile u (into plane (u+1)&1): A0@p0, B0@p1, B1@p2, A1@p3
//   = first-use order in tile u+1 (A0,B0 @p0; B1 @p1; A1 @p2).
// Gate: vmcnt(4)+s_barrier at p0,p1,p2 (4 half-tiles = 8 loads max in flight;
// each half has 3-4 phases ~2000cyc slack). NEVER vmcnt(0) in the loop.
// MODE 0: blend_act -> fp16 out.  MODE 1: relu -> fp16 out.
#define MFMA_QUAD(MH, NH) do {                                                      \
  __builtin_amdgcn_s_setprio(1);                                                    \
  _Pragma("unroll")                                                                 \
  for (int m = 0; m < 4; ++m)                                                       \
    _Pragma("unroll")                                                               \
    for (int n = 0; n < 2; ++n){                                                    \
      acc[(MH)*4+m][(NH)*2+n] = __builtin_amdgcn_mfma_f32_16x16x32_f16(             \
          af[m][0], bf[n][0], acc[(MH)*4+m][(NH)*2+n], 0, 0, 0);                    \
      acc[(MH)*4+m][(NH)*2+n] = __builtin_amdgcn_mfma_f32_16x16x32_f16(             \
          af[m][1], bf[n][1], acc[(MH)*4+m][(NH)*2+n], 0, 0, 0);                    \
    }                                                                               \
  __builtin_amdgcn_s_setprio(0);                                                    \
} while(0)

template<int MODE>
__global__ __launch_bounds__(512, 2)
void gemm_f16_256(const ushort* __restrict__ A, const ushort* __restrict__ Bw,
                  const float* __restrict__ bias, ushort* __restrict__ out,
                  int N, int K)
{
  __shared__ ushort lds[65536];
  const int t = threadIdx.x;
  const int lane = t & 63;
  const int w = t >> 6;
  const int wm = w >> 2, wn = w & 3;       // wave grid 2(M) x 4(N)
  const int ln15 = lane & 15, lnHi = lane >> 4;

  // XCD-aware bijective swizzle (nwg divisible by 8)
  const int gx = gridDim.x;
  const int nwg = gx * gridDim.y;
  const int bid = blockIdx.y * gx + blockIdx.x;
  const int swz = (bid & 7) * (nwg >> 3) + (bid >> 3);
  const int m0 = (swz / gx) * 256;
  const int n0 = (swz % gx) * 256;

  const ushort* gA = A + (size_t)m0 * K;
  const ushort* gB = Bw + (size_t)n0 * K;
  const int NT = K >> 6;

  // -------- staging constants (per thread: 2 chunks per half-tile) --------
  const int rh0  = t >> 3;                              // LDS row-in-half, chunk0 (0..63)
  const int slot = t & 7;                               // 16B slot in 128B row
  const int gkhw = ((slot << 4) ^ ((rh0 & 7) << 4)) >> 1;  // inv-swizzled k (halfwords)
  const int growB0_ = (rh0 >> 5) * 64 + (rh0 & 31);     // B global-row base (+nh*32)

  auto STAGE_A = [&](int mh, int u, int parn){
    const int r0 = mh * 64 + rh0;
    const size_t koff = (size_t)u * 64 + gkhw;
    ushort* dst = &lds[parn * 16384 + mh * 8192 + rh0 * 64 + slot * 8];
    gload16(gA + (size_t)r0 * K + koff, dst);
    gload16(gA + (size_t)(r0 + 128) * K + koff, dst + 4096);
  };
  auto STAGE_B = [&](int nh, int u, int parn){
    const int r0 = nh * 32 + growB0_;
    const size_t koff = (size_t)u * 64 + gkhw;
    ushort* dst = &lds[32768 + parn * 16384 + nh * 8192 + rh0 * 64 + slot * 8];
    gload16(gB + (size_t)r0 * K + koff, dst);
    gload16(gB + (size_t)(r0 + 128) * K + koff, dst + 4096);
  };

  // -------- fragment-read constants --------
  const int sw    = (ln15 & 7) << 4;                    // byte swizzle (row&7 == ln15&7)
  const int koff0 = ((lnHi * 16) ^ sw) >> 1;            // hw offset, k-step 0
  const int koff1 = koff0 ^ 32;                         // k-step 1 (+64B)
  const int rA_   = (wm * 64 + ln15) * 64;              // + m*1024
  const int rB_   = (wn * 32 + ln15) * 64;              // + n*1024

  f32x4 acc[8][4] = {};
  f16x8 af[4][2], bf[2][2];

  auto readA = [&](int par, int mh){
    const ushort* base = &lds[par * 16384 + mh * 8192 + rA_];
#pragma unroll
    for (int m = 0; m < 4; ++m){
      af[m][0] = *(const f16x8*)&base[m * 1024 + koff0];
      af[m][1] = *(const f16x8*)&base[m * 1024 + koff1];
    }
  };
  auto readB = [&](int par, int nh){
    const ushort* base = &lds[32768 + par * 16384 + nh * 8192 + rB_];
#pragma unroll
    for (int n = 0; n < 2; ++n){
      bf[n][0] = *(const f16x8*)&base[n * 1024 + koff0];
      bf[n][1] = *(const f16x8*)&base[n * 1024 + koff1];
    }
  };

  // -------- prologue: tile 0 -> plane 0, in first-use order --------
  STAGE_A(0, 0, 0);
  STAGE_B(0, 0, 0);
  STAGE_B(1, 0, 0);
  STAGE_A(1, 0, 0);

  for (int u = 0; u < NT; ++u){
    const int par = u & 1, parn = par ^ 1;
    // -- p0 (mh0,nh0): needs A0(u),B0(u)
    asm volatile("s_waitcnt vmcnt(4)" ::: "memory");
    __builtin_amdgcn_s_barrier();
    readA(par, 0);
    readB(par, 0);
    STAGE_A(0, u + 1, parn);
    MFMA_QUAD(0, 0);
    // -- p1 (mh0,nh1): needs B1(u); af reused
    asm volatile("s_waitcnt vmcnt(4)" ::: "memory");
    __builtin_amdgcn_s_barrier();
    readB(par, 1);
    STAGE_B(0, u + 1, parn);
    MFMA_QUAD(0, 1);
    // -- p2 (mh1,nh0): needs A1(u)
    asm volatile("s_waitcnt vmcnt(4)" ::: "memory");
    __builtin_amdgcn_s_barrier();
    readA(par, 1);
    readB(par, 0);
    STAGE_B(1, u + 1, parn);
    MFMA_QUAD(1, 0);
    // -- p3 (mh1,nh1): all halves already published; af reused
    __builtin_amdgcn_s_barrier();
    readB(par, 1);
    STAGE_A(1, u + 1, parn);
    MFMA_QUAD(1, 1);
  }

  // drain tail prefetches (vmcnt(0)) + publish before LDS reuse
  __syncthreads();

  // ---- epilogue: act -> fp16 -> LDS [256][256] (XOR swizzle) -> coalesced stores --
  const int rowbase = wm * 128 + lnHi * 4;
  const int colbase = wn * 64 + ln15;
#pragma unroll
  for (int j = 0; j < 4; ++j){
    const int col = colbase + j * 16;
    const float bv = bias[n0 + col];
#pragma unroll
    for (int i = 0; i < 8; ++i){
#pragma unroll
      for (int r = 0; r < 4; ++r){
        const int row = rowbase + i * 16 + r;
        const float v = acc[i][j][r] + bv;
        float a;
        if (MODE == 0){
          const float th = 1.f - 2.f / (__expf(2.f * v) + 1.f);  // tanh(v)
          a = v > 0.f ? v * 0.9f + th * 0.1f : th * 0.5f;
        } else {
          a = v > 0.f ? v : 0.f;
        }
        const _Float16 h = (_Float16)a;
        lds[row * 256 + (col ^ ((row & 7) << 3))] = __builtin_bit_cast(ushort, h);
      }
    }
  }
  __syncthreads();
#pragma unroll
  for (int it = 0; it < 16; ++it){
    const int chunk = it * 512 + t;            // 256 rows x 32 chunks of 8 halfwords
    const int row = chunk >> 5, g = chunk & 31;
    const s16x8 vv = *(const s16x8*)&lds[row * 256 + ((g ^ (row & 7)) << 3)];
    *(s16x8*)&out[(size_t)(m0 + row) * N + n0 + (g << 3)] = vv;
  }
}

// ---------------- tiny GEMM3: out[32768][10] = h2 @ W3 + b3 (fp32 vector) ---------
__global__ void gemm3(const ushort* __restrict__ h2, const float* __restrict__ W3T,
                      const float* __restrict__ b3, float* __restrict__ out){
  const int lane = threadIdx.x & 63;
  const int row = blockIdx.x * 4 + (threadIdx.x >> 6);  // one wave per row
  const f16x8 hv = *(const f16x8*)(h2 + (size_t)row * 512 + lane * 8);
  float hf[8];
#pragma unroll
  for (int j = 0; j < 8; ++j) hf[j] = (float)hv[j];
  float acc[10];
#pragma unroll
  for (int c = 0; c < 10; ++c){
    const f32x4 w0 = *(const f32x4*)(W3T + c * 512 + lane * 8);
    const f32x4 w1 = *(const f32x4*)(W3T + c * 512 + lane * 8 + 4);
    float a = 0.f;
#pragma unroll
    for (int j = 0; j < 4; ++j) a += hf[j] * w0[j];
#pragma unroll
    for (int j = 0; j < 4; ++j) a += hf[4 + j] * w1[j];
    acc[c] = a;
  }
#pragma unroll
  for (int off = 32; off; off >>= 1)
#pragma unroll
    for (int c = 0; c < 10; ++c) acc[c] += __shfl_xor(acc[c], off);
  if (lane == 0){
#pragma unroll
    for (int c = 0; c < 10; ++c) out[(size_t)row * 10 + c] = acc[c] + b3[c];
  }
}

extern "C" void kernel_launch(void* const* d_in, const int* in_sizes, int n_in,
                              void* d_out, int out_size, void* d_ws, size_t ws_size,
                              hipStream_t stream){
  const float* x  = (const float*)d_in[0];
  const float* W1 = (const float*)d_in[1];
  const float* b1 = (const float*)d_in[2];
  const float* W2 = (const float*)d_in[3];
  const float* b2 = (const float*)d_in[4];
  const float* W3 = (const float*)d_in[5];
  const float* b3 = (const float*)d_in[6];
  float* out = (float*)d_out;

  const int B = 32768, Din = 512, H = 1024, Hh = 512;
  char* ws = (char*)d_ws;
  const size_t MB = (size_t)1 << 20;
  // ws layout (~99 MB):
  ushort* h1  = (ushort*)(ws);            // 64 MB  (32768 x 1024 fp16)
  ushort* xf  = (ushort*)(ws + 64 * MB);  // 32 MB  (32768 x 512 fp16; reused as h2)
  ushort* h2  = xf;
  ushort* W1T = (ushort*)(ws + 96 * MB);  // 1 MB   (1024 x 512 fp16)
  ushort* W2T = (ushort*)(ws + 97 * MB);  // 1 MB   (512 x 1024 fp16)
  float*  W3T = (float*)(ws + 98 * MB);   // 20 KB  (10 x 512 f32)

  convert_f16<<<(B * Din / 4 + 255) / 256, 256, 0, stream>>>(x, xf, B * Din / 4);
  transpose_f16<<<dim3(H / 32, Din / 32), 256, 0, stream>>>(W1, W1T, Din, H);
  transpose_f16<<<dim3(Hh / 32, H / 32), 256, 0, stream>>>(W2, W2T, H, Hh);
  transpose_w3<<<1, 512, 0, stream>>>(W3, W3T);

  gemm_f16_256<0><<<dim3(H / 256, B / 256), 512, 0, stream>>>(xf, W1T, b1, h1, H, Din);
  gemm_f16_256<1><<<dim3(Hh / 256, B / 256), 512, 0, stream>>>(h1, W2T, b2, h2, Hh, H);
  gemm3<<<B / 4, 256, 0, stream>>>(h2, W3T, b3, out);
}

// Round 8
// 153.515 us; speedup vs baseline: 1.0037x; 1.0037x over previous
//
#include <hip/hip_runtime.h>
#include <hip/hip_bf16.h>
#include <hip/hip_fp16.h>
#include <cstdint>

typedef __attribute__((ext_vector_type(8))) short s16x8;
typedef __attribute__((ext_vector_type(4))) short s16x4;
typedef __attribute__((ext_vector_type(8))) _Float16 f16x8;
typedef __attribute__((ext_vector_type(4))) _Float16 f16x4;
typedef __attribute__((ext_vector_type(4))) float f32x4;

__device__ __forceinline__ void gload16(const void* g, void* l){
  __builtin_amdgcn_global_load_lds((const __attribute__((address_space(1))) void*)g,
                                   (__attribute__((address_space(3))) void*)l, 16, 0, 0);
}

// ---------------- pre-pass: fp32 -> fp16 ----------------
__global__ void convert_f16(const float* __restrict__ in, ushort* __restrict__ out, int n4){
  int i = blockIdx.x * blockDim.x + threadIdx.x;
  if (i >= n4) return;
  const f32x4 v = ((const f32x4*)in)[i];
  f16x4 o;
#pragma unroll
  for (int j = 0; j < 4; ++j) o[j] = (_Float16)v[j];
  ((f16x4*)out)[i] = o;
}

// transpose + convert: in[K][N] f32 -> outT[N][K] fp16
__global__ void transpose_f16(const float* __restrict__ in, ushort* __restrict__ outT,
                              int K, int N){
  __shared__ float tile[32][33];
  const int kb = blockIdx.y * 32, nb = blockIdx.x * 32;
  const int tx = threadIdx.x & 31, ty = threadIdx.x >> 5;  // ty: 0..7
#pragma unroll
  for (int r = 0; r < 32; r += 8)
    tile[ty + r][tx] = in[(size_t)(kb + ty + r) * N + nb + tx];
  __syncthreads();
#pragma unroll
  for (int r = 0; r < 32; r += 8){
    const float v = tile[tx][ty + r];
    const _Float16 h = (_Float16)v;
    outT[(size_t)(nb + ty + r) * K + kb + tx] = __builtin_bit_cast(ushort, h);
  }
}

// W3 (512x10 f32) -> W3T (10x512 f32)
__global__ void transpose_w3(const float* __restrict__ W3, float* __restrict__ W3T){
  const int k = threadIdx.x;  // 512 threads
#pragma unroll
  for (int c = 0; c < 10; ++c) W3T[c * 512 + k] = W3[k * 10 + c];
}

// ---- 256x256-tile fp16 GEMM, m201-style phase interior ----------------------
// Per phase: ds_reads (pre-barrier) ; stage 1 half ; vmcnt(4) ; s_barrier ;
//            lgkmcnt(0)+sched_barrier ; setprio(1) 16xMFMA setprio(0) ; s_barrier.
// Stage order per K-tile u (into plane (u+1)&1): A0@p0 B0@p1 B1@p2 A1@p3
//   = first-use order at tile u+1 (A0,B0@p0; B1@p1; A1@p2).
// Publication: half staged at phase q is gated by the vmcnt(4)+barrier at the
// phase before its first read (3-4 phases of HBM slack). WAR at plane switch is
// gated by the post-MFMA barrier (readers drain lgkm before MFMA). Last tile
// peeled: no stages, vmcnt(2)@p0, vmcnt(0)@p1.
#define MFMA_QUAD(MH, NH) do {                                                      \
  __builtin_amdgcn_s_setprio(1);                                                    \
  _Pragma("unroll")                                                                 \
  for (int m = 0; m < 4; ++m)                                                       \
    _Pragma("unroll")                                                               \
    for (int n = 0; n < 2; ++n){                                                    \
      acc[(MH)*4+m][(NH)*2+n] = __builtin_amdgcn_mfma_f32_16x16x32_f16(             \
          af[m][0], bf[n][0], acc[(MH)*4+m][(NH)*2+n], 0, 0, 0);                    \
      acc[(MH)*4+m][(NH)*2+n] = __builtin_amdgcn_mfma_f32_16x16x32_f16(             \
          af[m][1], bf[n][1], acc[(MH)*4+m][(NH)*2+n], 0, 0, 0);                    \
    }                                                                               \
  __builtin_amdgcn_s_setprio(0);                                                    \
} while(0)

#define BAR()    asm volatile("s_barrier" ::: "memory")
#define VMC(N)   asm volatile("s_waitcnt vmcnt(" #N ")" ::: "memory")
#define LGKM0()  do { asm volatile("s_waitcnt lgkmcnt(0)" ::: "memory");            \
                      __builtin_amdgcn_sched_barrier(0); } while(0)

template<int MODE>
__global__ __launch_bounds__(512, 2)
void gemm_f16_256(const ushort* __restrict__ A, const ushort* __restrict__ Bw,
                  const float* __restrict__ bias, ushort* __restrict__ out,
                  int N, int K)
{
  __shared__ ushort lds[65536];
  const int t = threadIdx.x;
  const int lane = t & 63;
  const int w = t >> 6;
  const int wm = w >> 2, wn = w & 3;       // wave grid 2(M) x 4(N)
  const int ln15 = lane & 15, lnHi = lane >> 4;

  // XCD-aware bijective swizzle (nwg divisible by 8)
  const int gx = gridDim.x;
  const int nwg = gx * gridDim.y;
  const int bid = blockIdx.y * gx + blockIdx.x;
  const int swz = (bid & 7) * (nwg >> 3) + (bid >> 3);
  const int m0 = (swz / gx) * 256;
  const int n0 = (swz % gx) * 256;

  const ushort* gA = A + (size_t)m0 * K;
  const ushort* gB = Bw + (size_t)n0 * K;
  const int NT = K >> 6;

  // -------- staging constants (per thread: 2 chunks per half-tile) --------
  const int rh0  = t >> 3;                              // LDS row-in-half, chunk0 (0..63)
  const int slot = t & 7;                               // 16B slot in 128B row
  const int gkhw = ((slot << 4) ^ ((rh0 & 7) << 4)) >> 1;  // inv-swizzled k (halfwords)
  const int growB0_ = (rh0 >> 5) * 64 + (rh0 & 31);     // B global-row base (+nh*32)

  auto STAGE_A = [&](int mh, int u, int parn){
    const int r0 = mh * 64 + rh0;
    const size_t koff = (size_t)u * 64 + gkhw;
    ushort* dst = &lds[parn * 16384 + mh * 8192 + rh0 * 64 + slot * 8];
    gload16(gA + (size_t)r0 * K + koff, dst);
    gload16(gA + (size_t)(r0 + 128) * K + koff, dst + 4096);
  };
  auto STAGE_B = [&](int nh, int u, int parn){
    const int r0 = nh * 32 + growB0_;
    const size_t koff = (size_t)u * 64 + gkhw;
    ushort* dst = &lds[32768 + parn * 16384 + nh * 8192 + rh0 * 64 + slot * 8];
    gload16(gB + (size_t)r0 * K + koff, dst);
    gload16(gB + (size_t)(r0 + 128) * K + koff, dst + 4096);
  };

  // -------- fragment-read constants --------
  const int sw    = (ln15 & 7) << 4;                    // byte swizzle (row&7 == ln15&7)
  const int koff0 = ((lnHi * 16) ^ sw) >> 1;            // hw offset, k-step 0
  const int koff1 = koff0 ^ 32;                         // k-step 1 (+64B)
  const int rA_   = (wm * 64 + ln15) * 64;              // + m*1024
  const int rB_   = (wn * 32 + ln15) * 64;              // + n*1024

  f32x4 acc[8][4] = {};
  f16x8 af[4][2], bf[2][2];

  auto readA = [&](int par, int mh){
    const ushort* base = &lds[par * 16384 + mh * 8192 + rA_];
#pragma unroll
    for (int m = 0; m < 4; ++m){
      af[m][0] = *(const f16x8*)&base[m * 1024 + koff0];
      af[m][1] = *(const f16x8*)&base[m * 1024 + koff1];
    }
  };
  auto readB = [&](int par, int nh){
    const ushort* base = &lds[32768 + par * 16384 + nh * 8192 + rB_];
#pragma unroll
    for (int n = 0; n < 2; ++n){
      bf[n][0] = *(const f16x8*)&base[n * 1024 + koff0];
      bf[n][1] = *(const f16x8*)&base[n * 1024 + koff1];
    }
  };

  // -------- prologue: tile 0 -> plane 0, first-use order; publish A0,B0 ------
  STAGE_A(0, 0, 0);
  STAGE_B(0, 0, 0);
  STAGE_B(1, 0, 0);
  STAGE_A(1, 0, 0);
  VMC(4);
  BAR();

  for (int u = 0; u < NT - 1; ++u){
    const int par = u & 1, parn = par ^ 1;
    // -- p0 (mh0,nh0)
    readA(par, 0); readB(par, 0);
    STAGE_A(0, u + 1, parn);
    VMC(4); BAR(); LGKM0();
    MFMA_QUAD(0, 0);
    BAR();
    // -- p1 (mh0,nh1)
    readB(par, 1);
    STAGE_B(0, u + 1, parn);
    VMC(4); BAR(); LGKM0();
    MFMA_QUAD(0, 1);
    BAR();
    // -- p2 (mh1,nh0)
    readA(par, 1); readB(par, 0);
    STAGE_B(1, u + 1, parn);
    VMC(4); BAR(); LGKM0();
    MFMA_QUAD(1, 0);
    BAR();
    // -- p3 (mh1,nh1)
    readB(par, 1);
    STAGE_A(1, u + 1, parn);
    VMC(4); BAR(); LGKM0();
    MFMA_QUAD(1, 1);
    BAR();
  }
  // -------- peeled last tile (no stages; drain only here) --------
  {
    const int par = (NT - 1) & 1;
    readA(par, 0); readB(par, 0);
    VMC(2); BAR(); LGKM0();
    MFMA_QUAD(0, 0);
    BAR();
    readB(par, 1);
    VMC(0); BAR(); LGKM0();
    MFMA_QUAD(0, 1);
    BAR();
    readA(par, 1); readB(par, 0);
    BAR(); LGKM0();
    MFMA_QUAD(1, 0);
    BAR();
    readB(par, 1);
    BAR(); LGKM0();
    MFMA_QUAD(1, 1);
  }

  __syncthreads();

  // ---- epilogue: act -> fp16 -> LDS [256][256] (XOR swizzle) -> coalesced stores --
  const int rowbase = wm * 128 + lnHi * 4;
  const int colbase = wn * 64 + ln15;
#pragma unroll
  for (int j = 0; j < 4; ++j){
    const int col = colbase + j * 16;
    const float bv = bias[n0 + col];
#pragma unroll
    for (int i = 0; i < 8; ++i){
#pragma unroll
      for (int r = 0; r < 4; ++r){
        const int row = rowbase + i * 16 + r;
        const float v = acc[i][j][r] + bv;
        float a;
        if (MODE == 0){
          const float th = 1.f - 2.f / (__expf(2.f * v) + 1.f);  // tanh(v)
          a = v > 0.f ? v * 0.9f + th * 0.1f : th * 0.5f;
        } else {
          a = v > 0.f ? v : 0.f;
        }
        const _Float16 h = (_Float16)a;
        lds[row * 256 + (col ^ ((row & 7) << 3))] = __builtin_bit_cast(ushort, h);
      }
    }
  }
  __syncthreads();
#pragma unroll
  for (int it = 0; it < 16; ++it){
    const int chunk = it * 512 + t;            // 256 rows x 32 chunks of 8 halfwords
    const int row = chunk >> 5, g = chunk & 31;
    const s16x8 vv = *(const s16x8*)&lds[row * 256 + ((g ^ (row & 7)) << 3)];
    *(s16x8*)&out[(size_t)(m0 + row) * N + n0 + (g << 3)] = vv;
  }
}

// ---------------- tiny GEMM3: out[32768][10] = h2 @ W3 + b3 (fp32 vector) ---------
__global__ void gemm3(const ushort* __restrict__ h2, const float* __restrict__ W3T,
                      const float* __restrict__ b3, float* __restrict__ out){
  const int lane = threadIdx.x & 63;
  const int row = blockIdx.x * 4 + (threadIdx.x >> 6);  // one wave per row
  const f16x8 hv = *(const f16x8*)(h2 + (size_t)row * 512 + lane * 8);
  float hf[8];
#pragma unroll
  for (int j = 0; j < 8; ++j) hf[j] = (float)hv[j];
  float acc[10];
#pragma unroll
  for (int c = 0; c < 10; ++c){
    const f32x4 w0 = *(const f32x4*)(W3T + c * 512 + lane * 8);
    const f32x4 w1 = *(const f32x4*)(W3T + c * 512 + lane * 8 + 4);
    float a = 0.f;
#pragma unroll
    for (int j = 0; j < 4; ++j) a += hf[j] * w0[j];
#pragma unroll
    for (int j = 0; j < 4; ++j) a += hf[4 + j] * w1[j];
    acc[c] = a;
  }
#pragma unroll
  for (int off = 32; off; off >>= 1)
#pragma unroll
    for (int c = 0; c < 10; ++c) acc[c] += __shfl_xor(acc[c], off);
  if (lane == 0){
#pragma unroll
    for (int c = 0; c < 10; ++c) out[(size_t)row * 10 + c] = acc[c] + b3[c];
  }
}

extern "C" void kernel_launch(void* const* d_in, const int* in_sizes, int n_in,
                              void* d_out, int out_size, void* d_ws, size_t ws_size,
                              hipStream_t stream){
  const float* x  = (const float*)d_in[0];
  const float* W1 = (const float*)d_in[1];
  const float* b1 = (const float*)d_in[2];
  const float* W2 = (const float*)d_in[3];
  const float* b2 = (const float*)d_in[4];
  const float* W3 = (const float*)d_in[5];
  const float* b3 = (const float*)d_in[6];
  float* out = (float*)d_out;

  const int B = 32768, Din = 512, H = 1024, Hh = 512;
  char* ws = (char*)d_ws;
  const size_t MB = (size_t)1 << 20;
  // ws layout (~99 MB):
  ushort* h1  = (ushort*)(ws);            // 64 MB  (32768 x 1024 fp16)
  ushort* xf  = (ushort*)(ws + 64 * MB);  // 32 MB  (32768 x 512 fp16; reused as h2)
  ushort* h2  = xf;
  ushort* W1T = (ushort*)(ws + 96 * MB);  // 1 MB   (1024 x 512 fp16)
  ushort* W2T = (ushort*)(ws + 97 * MB);  // 1 MB   (512 x 1024 fp16)
  float*  W3T = (float*)(ws + 98 * MB);   // 20 KB  (10 x 512 f32)

  convert_f16<<<(B * Din / 4 + 255) / 256, 256, 0, stream>>>(x, xf, B * Din / 4);
  transpose_f16<<<dim3(H / 32, Din / 32), 256, 0, stream>>>(W1, W1T, Din, H);
  transpose_f16<<<dim3(Hh / 32, H / 32), 256, 0, stream>>>(W2, W2T, H, Hh);
  transpose_w3<<<1, 512, 0, stream>>>(W3, W3T);

  gemm_f16_256<0><<<dim3(H / 256, B / 256), 512, 0, stream>>>(xf, W1T, b1, h1, H, Din);
  gemm_f16_256<1><<<dim3(Hh / 256, B / 256), 512, 0, stream>>>(h1, W2T, b2, h2, Hh, H);
  gemm3<<<B / 4, 256, 0, stream>>>(h2, W3T, b3, out);
}